// Round 9
// baseline (390.586 us; speedup 1.0000x reference)
//
#include <hip/hip_runtime.h>
#include <math.h>

#define N_    16
#define CIN_  16
#define T_    512
#define V_    200
#define K_    3
#define COUT_ 64
#define H_    64
#define G_    256  // 4*H

// Workspace layout (float offsets):
//   a  : [0, 600)                 a[k][v] = sum_w A[k,v,w] / V
//   sa : [640, 643)               sa[k] = sum_{v,w} A[k,v,w] / V
//   xa : [1024, 1024+16*512*48)   xa[n][t][k*16+ci]
//   xW : [WS_XW, +512*16*256)     xW[t][n][g]  (gate pre-activations, input side)
#define WS_A  0
#define WS_SA 640
#define WS_XA 1024
#define WS_XW (WS_XA + N_ * T_ * K_ * CIN_)

// fast activations: v_exp_f32-based, ~1e-6 rel err, saturate correctly
__device__ __forceinline__ float fast_sig(float x) {
    return __builtin_amdgcn_rcpf(1.f + __expf(-x));
}
__device__ __forceinline__ float fast_tanh(float x) {
    return fmaf(-2.f, __builtin_amdgcn_rcpf(1.f + __expf(2.f * x)), 1.f);
}

// ---------------------------------------------------------------------------
// Kernel 1 (fused prep): blocks [0, NCOPY) copy A->out[16:] (and blocks 0-2
// also compute a[k][v]); blocks NCOPY+k (k=0..2) reduce A[k] to sa[k].
#define NCOPY ((K_ * V_ * V_ + 255) / 256)
__global__ __launch_bounds__(256) void prep_kernel(const float* __restrict__ A,
                                                   float* __restrict__ out,
                                                   float* __restrict__ ws) {
    int b = blockIdx.x;
    if (b < NCOPY) {
        int tid = b * 256 + threadIdx.x;
        if (tid < K_ * V_ * V_) out[16 + tid] = A[tid];
        if (tid < K_ * V_) {
            const float* row = A + (long)tid * V_;
            float s = 0.f;
            for (int w = 0; w < V_; ++w) s += row[w];
            ws[WS_A + tid] = s * (1.0f / V_);
        }
    } else {
        int k = b - NCOPY;                      // 0..2
        const float* Ak = A + (long)k * V_ * V_;
        float s = 0.f;
        for (int i = threadIdx.x; i < V_ * V_; i += 256) s += Ak[i];
        #pragma unroll
        for (int m = 1; m < 64; m <<= 1) s += __shfl_xor(s, m);
        __shared__ float red[4];
        if ((threadIdx.x & 63) == 0) red[threadIdx.x >> 6] = s;
        __syncthreads();
        if (threadIdx.x == 0)
            ws[WS_SA + k] = (red[0] + red[1] + red[2] + red[3]) * (1.0f / V_);
    }
}

// ---------------------------------------------------------------------------
// Kernel 2: xa[n][t][k*16+ci] = sum_v x[n][ci][t][v] * a[k][v]
// One wave per (n,ci,t) row; lanes stride over v (coalesced).
__global__ __launch_bounds__(256) void xa_kernel(const float* __restrict__ x,
                                                 float* __restrict__ ws) {
    __shared__ float aS[K_ * V_];
    int tid = threadIdx.x;
    for (int i = tid; i < K_ * V_; i += 256) aS[i] = ws[WS_A + i];
    __syncthreads();

    int wave = tid >> 6, lane = tid & 63;
    int row = blockIdx.x * 4 + wave;          // row = (n*CIN + ci)*T + t
    const float* xr = x + (long)row * V_;

    float s0 = 0.f, s1 = 0.f, s2 = 0.f;
    for (int v = lane; v < V_; v += 64) {
        float xv = xr[v];
        s0 = fmaf(xv, aS[v], s0);
        s1 = fmaf(xv, aS[V_ + v], s1);
        s2 = fmaf(xv, aS[2 * V_ + v], s2);
    }
    #pragma unroll
    for (int m = 1; m < 64; m <<= 1) {
        s0 += __shfl_xor(s0, m);
        s1 += __shfl_xor(s1, m);
        s2 += __shfl_xor(s2, m);
    }
    if (lane == 0) {
        int t  = row % T_;
        int nc = row / T_;
        int ci = nc % CIN_;
        int n  = nc / CIN_;
        long base = (long)(n * T_ + t) * (K_ * CIN_);
        ws[WS_XA + base + 0 * CIN_ + ci] = s0;
        ws[WS_XA + base + 1 * CIN_ + ci] = s1;
        ws[WS_XA + base + 2 * CIN_ + ci] = s2;
    }
}

// ---------------------------------------------------------------------------
// Kernel 3 (fused seq + input-gate GEMM): ONE block per t (512 blocks).
__global__ __launch_bounds__(256) void seqgates_kernel(
    const float* __restrict__ W_gcn, const float* __restrict__ b_gcn,
    const float* __restrict__ W_ih, const float* __restrict__ b_ih,
    const float* __restrict__ b_hh, float* __restrict__ ws) {
    int t = blockIdx.x;
    int tid = threadIdx.x;
    __shared__ float xaS[N_][K_ * CIN_];
    __shared__ __align__(16) float seqS[N_][COUT_];
    __shared__ float saS[K_];

    if (tid < K_) saS[tid] = ws[WS_SA + tid];
    #pragma unroll
    for (int r = 0; r < 3; ++r) {
        int i = tid + r * 256;
        if (i < N_ * K_ * CIN_) {
            int n = i / (K_ * CIN_), kc = i % (K_ * CIN_);
            xaS[n][kc] = ws[WS_XA + (long)(n * T_ + t) * (K_ * CIN_) + kc];
        }
    }
    __syncthreads();

    // Phase 1: thread (n = tid>>4, c0 = (tid&15)*4) computes 4 seq entries.
    {
        int n = tid >> 4, c0 = (tid & 15) * 4;
        #pragma unroll
        for (int cc = 0; cc < 4; ++cc) {
            int c = c0 + cc;
            float s = 0.f;
            #pragma unroll
            for (int k = 0; k < K_; ++k) {
                s = fmaf(b_gcn[k * COUT_ + c], saS[k], s);
                const float* wrow = W_gcn + (long)(k * COUT_ + c) * CIN_;
                #pragma unroll
                for (int ci = 0; ci < CIN_; ++ci)
                    s = fmaf(wrow[ci], xaS[n][k * CIN_ + ci], s);
            }
            seqS[n][c] = s;
        }
    }
    __syncthreads();

    // Phase 2: thread g: 16 accumulators over n; W_ih row streamed as float4.
    {
        int g = tid;
        float acc[N_];
        #pragma unroll
        for (int n = 0; n < N_; ++n) acc[n] = 0.f;
        const float4* wrow4 = (const float4*)(W_ih + (long)g * H_);
        #pragma unroll
        for (int c4 = 0; c4 < H_ / 4; ++c4) {
            float4 w4 = wrow4[c4];
            #pragma unroll
            for (int n = 0; n < N_; ++n) {
                float4 s4 = ((const float4*)seqS[n])[c4];  // LDS broadcast
                acc[n] = fmaf(w4.x, s4.x, acc[n]);
                acc[n] = fmaf(w4.y, s4.y, acc[n]);
                acc[n] = fmaf(w4.z, s4.z, acc[n]);
                acc[n] = fmaf(w4.w, s4.w, acc[n]);
            }
        }
        float bias = b_ih[g] + b_hh[g];
        #pragma unroll
        for (int n = 0; n < N_; ++n)
            ws[WS_XW + (long)(t * N_ + n) * G_ + g] = acc[n] + bias;
    }
}

// ---------------------------------------------------------------------------
// Kernel 4: sequential LSTM scan — R3 structure, but W_hh STAGED IN LDS.
// R2-R7 evidence: the compiler never keeps 64 weights/thread in VGPRs, so
// each step re-streamed 64KB of W_hh from L2. Per-CU L2 BW ~56 B/cyc ->
// ~1170 cyc/step, matching the measured 1280. LDS streams at 256 B/cyc ->
// floor 256 cyc/step. Wst is float4-interleaved: thread g reads Wst[i][g],
// lane-consecutive 16B -> canonical conflict-free ds_read_b128.
__global__ __launch_bounds__(256, 1) void lstm_kernel(
    const float* __restrict__ W_hh, const float* __restrict__ W_fc,
    const float* __restrict__ b_fc, const float* __restrict__ ws,
    float* __restrict__ out) {
    int n = blockIdx.x;
    int w = threadIdx.x >> 6;     // gate type (torch order: i,f,g,o)
    int lane = threadIdx.x & 63;  // gate index / h index
    int g = threadIdx.x;          // gate row 0..255

    __shared__ __align__(16) float4 Wst[16][G_];   // 64 KB staged W_hh
    __shared__ __align__(16) float hS[H_];
    __shared__ float gbuf[4][H_];

    // One-time stage: thread g owns row g of W_hh.
    {
        const float4* wr = (const float4*)(W_hh + (long)g * H_);
        #pragma unroll
        for (int i = 0; i < 16; ++i) Wst[i][g] = wr[i];
    }
    if (threadIdx.x < H_) hS[threadIdx.x] = 0.f;
    float ccell = 0.f, hlast = 0.f;   // live only in wave 0
    __syncthreads();

    const float* xw = ws + WS_XW + (long)n * G_ + g;
    // depth-2 prefetch of the input-side gate pre-activations
    float x0 = xw[0];
    float x1 = xw[(long)N_ * G_];

    for (int t = 0; t < T_; ++t) {
        float gate = x0;
        x0 = x1;
        if (t + 2 < T_) x1 = xw[(long)(t + 2) * N_ * G_];

        // gate += dot(W row, h): W streamed from LDS (conflict-free b128),
        // h from uniform-address broadcast b128; 4 accumulators for ILP.
        float a0 = 0.f, a1 = 0.f, a2 = 0.f, a3 = 0.f;
        const float4* h4 = (const float4*)hS;
        #pragma unroll
        for (int i = 0; i < 16; ++i) {
            float4 wv = Wst[i][g];
            float4 hv = h4[i];
            a0 = fmaf(wv.x, hv.x, a0);
            a1 = fmaf(wv.y, hv.y, a1);
            a2 = fmaf(wv.z, hv.z, a2);
            a3 = fmaf(wv.w, hv.w, a3);
        }
        gate += (a0 + a1) + (a2 + a3);

        gbuf[w][lane] = gate;
        __syncthreads();               // B1: gates visible
        if (w == 0) {
            float iv = fast_sig(gate);           // own gate == i
            float fv = fast_sig(gbuf[1][lane]);
            float gv = fast_tanh(gbuf[2][lane]);
            float ov = fast_sig(gbuf[3][lane]);
            ccell = fmaf(fv, ccell, iv * gv);
            hlast = ov * fast_tanh(ccell);
            hS[lane] = hlast;
        }
        __syncthreads();               // B2: new h visible
    }

    if (w == 0) {
        float p = hlast * W_fc[lane];
        #pragma unroll
        for (int m = 1; m < 64; m <<= 1) p += __shfl_xor(p, m);
        if (lane == 0) out[n] = p + b_fc[0];
    }
}

// ---------------------------------------------------------------------------
extern "C" void kernel_launch(void* const* d_in, const int* in_sizes, int n_in,
                              void* d_out, int out_size, void* d_ws, size_t ws_size,
                              hipStream_t stream) {
    const float* x     = (const float*)d_in[0];
    const float* A     = (const float*)d_in[1];
    const float* W_gcn = (const float*)d_in[2];
    const float* b_gcn = (const float*)d_in[3];
    const float* W_ih  = (const float*)d_in[4];
    const float* W_hh  = (const float*)d_in[5];
    const float* b_ih  = (const float*)d_in[6];
    const float* b_hh  = (const float*)d_in[7];
    const float* W_fc  = (const float*)d_in[8];
    const float* b_fc  = (const float*)d_in[9];
    float* out = (float*)d_out;
    float* ws  = (float*)d_ws;

    // 1) fused: copy A->out, a[k][v], sa[k]
    prep_kernel<<<NCOPY + K_, 256, 0, stream>>>(A, out, ws);
    // 2) xa
    int rows = N_ * CIN_ * T_;             // 131072 rows, one wave each
    xa_kernel<<<rows / 4, 256, 0, stream>>>(x, ws);
    // 3) fused seq + input-side gate GEMM (one block per t)
    seqgates_kernel<<<T_, 256, 0, stream>>>(W_gcn, b_gcn, W_ih, b_ih, b_hh, ws);
    // 4) sequential LSTM scan + final FC
    lstm_kernel<<<N_, 256, 0, stream>>>(W_hh, W_fc, b_fc, ws, out);
}

// Round 10
// 366.604 us; speedup vs baseline: 1.0654x; 1.0654x over previous
//
#include <hip/hip_runtime.h>
#include <math.h>

#define N_    16
#define CIN_  16
#define T_    512
#define V_    200
#define K_    3
#define COUT_ 64
#define H_    64
#define G_    256  // 4*H

// Workspace layout (float offsets):
//   a  : [0, 600)                 a[k][v] = sum_w A[k,v,w] / V
//   sa : [640, 643)               sa[k] = sum_{v,w} A[k,v,w] / V
//   xa : [1024, 1024+16*512*48)   xa[n][t][k*16+ci]
//   xW : [WS_XW, +512*16*256)     xW[t][n][g]  (gate pre-activations, input side)
#define WS_A  0
#define WS_SA 640
#define WS_XA 1024
#define WS_XW (WS_XA + N_ * T_ * K_ * CIN_)

// fast activations: v_exp_f32-based, ~1e-6 rel err, saturate correctly
__device__ __forceinline__ float fast_sig(float x) {
    return __builtin_amdgcn_rcpf(1.f + __expf(-x));
}
__device__ __forceinline__ float fast_tanh(float x) {
    return fmaf(-2.f, __builtin_amdgcn_rcpf(1.f + __expf(2.f * x)), 1.f);
}

// ---------------------------------------------------------------------------
// Kernel 1 (fused prep): blocks [0, NCOPY) copy A->out[16:] (and blocks 0-2
// also compute a[k][v]); blocks NCOPY+k (k=0..2) reduce A[k] to sa[k].
#define NCOPY ((K_ * V_ * V_ + 255) / 256)
__global__ __launch_bounds__(256) void prep_kernel(const float* __restrict__ A,
                                                   float* __restrict__ out,
                                                   float* __restrict__ ws) {
    int b = blockIdx.x;
    if (b < NCOPY) {
        int tid = b * 256 + threadIdx.x;
        if (tid < K_ * V_ * V_) out[16 + tid] = A[tid];
        if (tid < K_ * V_) {
            const float* row = A + (long)tid * V_;
            float s = 0.f;
            for (int w = 0; w < V_; ++w) s += row[w];
            ws[WS_A + tid] = s * (1.0f / V_);
        }
    } else {
        int k = b - NCOPY;                      // 0..2
        const float* Ak = A + (long)k * V_ * V_;
        float s = 0.f;
        for (int i = threadIdx.x; i < V_ * V_; i += 256) s += Ak[i];
        #pragma unroll
        for (int m = 1; m < 64; m <<= 1) s += __shfl_xor(s, m);
        __shared__ float red[4];
        if ((threadIdx.x & 63) == 0) red[threadIdx.x >> 6] = s;
        __syncthreads();
        if (threadIdx.x == 0)
            ws[WS_SA + k] = (red[0] + red[1] + red[2] + red[3]) * (1.0f / V_);
    }
}

// ---------------------------------------------------------------------------
// Kernel 2 (NEW tiled xa): xa[n][t][k*16+ci] = sum_v x[n][ci][t][v] * a[k][v]
// One block per (n, ci, 64-t chunk): load the contiguous 64x200 tile into
// padded LDS with float4s, then thread (t_local, k) serially dots its row.
// NO cross-lane ops (old version: 18 shfl/bpermute per 800-B row ~= 46us of
// LDS-pipe time across the dispatch).
#define TT 64
#define PADV 204   // 204 % 4 == 0 -> b128-aligned rows; full-rate b128 reads
__global__ __launch_bounds__(256) void xa_kernel(const float* __restrict__ x,
                                                 float* __restrict__ ws) {
    __shared__ __align__(16) float xt[TT * PADV];
    __shared__ __align__(16) float aS[K_ * V_];
    int tid = threadIdx.x;
    int b = blockIdx.x;
    int tchunk = b & 7;
    int ci = (b >> 3) & 15;
    int n = b >> 7;
    int t0 = tchunk * TT;

    for (int i = tid; i < K_ * V_; i += 256) aS[i] = ws[WS_A + i];

    // coalesced float4 load of the tile (64 rows x 50 float4, contiguous)
    const float4* xg4 =
        (const float4*)(x + ((long)(n * CIN_ + ci) * T_ + t0) * V_);
    for (int j = tid; j < TT * (V_ / 4); j += 256) {
        float4 v = xg4[j];
        int t = j / (V_ / 4), v4 = (j % (V_ / 4)) * 4;
        *(float4*)(xt + t * PADV + v4) = v;
    }
    __syncthreads();

    int t_local = tid & 63;
    int k = tid >> 6;            // waves 0..2 active, wave 3 idle
    if (k < K_) {
        const float* xr = xt + t_local * PADV;
        const float* ar = aS + k * V_;
        float a0 = 0.f, a1 = 0.f, a2 = 0.f, a3 = 0.f;
        #pragma unroll 5
        for (int v4 = 0; v4 < V_; v4 += 4) {
            float4 xv = *(const float4*)(xr + v4);
            float4 av = *(const float4*)(ar + v4);   // wave-uniform broadcast
            a0 = fmaf(xv.x, av.x, a0);
            a1 = fmaf(xv.y, av.y, a1);
            a2 = fmaf(xv.z, av.z, a2);
            a3 = fmaf(xv.w, av.w, a3);
        }
        float s = (a0 + a1) + (a2 + a3);
        ws[WS_XA + ((long)n * T_ + (t0 + t_local)) * (K_ * CIN_) + k * CIN_ + ci] = s;
    }
}

// ---------------------------------------------------------------------------
// Kernel 3 (fused seq + input-gate GEMM): ONE block per t (512 blocks).
__global__ __launch_bounds__(256) void seqgates_kernel(
    const float* __restrict__ W_gcn, const float* __restrict__ b_gcn,
    const float* __restrict__ W_ih, const float* __restrict__ b_ih,
    const float* __restrict__ b_hh, float* __restrict__ ws) {
    int t = blockIdx.x;
    int tid = threadIdx.x;
    __shared__ float xaS[N_][K_ * CIN_];
    __shared__ __align__(16) float seqS[N_][COUT_];
    __shared__ float saS[K_];

    if (tid < K_) saS[tid] = ws[WS_SA + tid];
    #pragma unroll
    for (int r = 0; r < 3; ++r) {
        int i = tid + r * 256;
        if (i < N_ * K_ * CIN_) {
            int n = i / (K_ * CIN_), kc = i % (K_ * CIN_);
            xaS[n][kc] = ws[WS_XA + (long)(n * T_ + t) * (K_ * CIN_) + kc];
        }
    }
    __syncthreads();

    // Phase 1: thread (n = tid>>4, c0 = (tid&15)*4) computes 4 seq entries.
    {
        int n = tid >> 4, c0 = (tid & 15) * 4;
        #pragma unroll
        for (int cc = 0; cc < 4; ++cc) {
            int c = c0 + cc;
            float s = 0.f;
            #pragma unroll
            for (int k = 0; k < K_; ++k) {
                s = fmaf(b_gcn[k * COUT_ + c], saS[k], s);
                const float* wrow = W_gcn + (long)(k * COUT_ + c) * CIN_;
                #pragma unroll
                for (int ci = 0; ci < CIN_; ++ci)
                    s = fmaf(wrow[ci], xaS[n][k * CIN_ + ci], s);
            }
            seqS[n][c] = s;
        }
    }
    __syncthreads();

    // Phase 2: thread g: 16 accumulators over n; W_ih row streamed as float4.
    {
        int g = tid;
        float acc[N_];
        #pragma unroll
        for (int n = 0; n < N_; ++n) acc[n] = 0.f;
        const float4* wrow4 = (const float4*)(W_ih + (long)g * H_);
        #pragma unroll
        for (int c4 = 0; c4 < H_ / 4; ++c4) {
            float4 w4 = wrow4[c4];
            #pragma unroll
            for (int n = 0; n < N_; ++n) {
                float4 s4 = ((const float4*)seqS[n])[c4];  // LDS broadcast
                acc[n] = fmaf(w4.x, s4.x, acc[n]);
                acc[n] = fmaf(w4.y, s4.y, acc[n]);
                acc[n] = fmaf(w4.z, s4.z, acc[n]);
                acc[n] = fmaf(w4.w, s4.w, acc[n]);
            }
        }
        float bias = b_ih[g] + b_hh[g];
        #pragma unroll
        for (int n = 0; n < N_; ++n)
            ws[WS_XW + (long)(t * N_ + n) * G_ + g] = acc[n] + bias;
    }
}

// ---------------------------------------------------------------------------
// Kernel 4: sequential LSTM scan — R7 verbatim (measured floor: 273us; R9's
// LDS-staged variant was 277.5 -> reverted).
__global__ __launch_bounds__(256, 1) void lstm_kernel(
    const float* __restrict__ W_hh, const float* __restrict__ W_fc,
    const float* __restrict__ b_fc, const float* __restrict__ ws,
    float* __restrict__ out) {
    int n = blockIdx.x;
    int w = threadIdx.x >> 6;     // gate type (torch order: i,f,g,o)
    int lane = threadIdx.x & 63;  // gate index / h index

    const float4* wr = (const float4*)(W_hh + (long)(w * H_ + lane) * H_);
    float4 w0  = wr[0],  w1  = wr[1],  w2  = wr[2],  w3  = wr[3];
    float4 w4  = wr[4],  w5  = wr[5],  w6  = wr[6],  w7  = wr[7];
    float4 w8  = wr[8],  w9  = wr[9],  w10 = wr[10], w11 = wr[11];
    float4 w12 = wr[12], w13 = wr[13], w14 = wr[14], w15 = wr[15];

    __shared__ __align__(16) float hS[H_];
    __shared__ float gbuf[4][H_];

    if (threadIdx.x < H_) hS[threadIdx.x] = 0.f;
    float ccell = 0.f, hlast = 0.f;   // live only in wave 0
    __syncthreads();

    const float* xw = ws + WS_XW + (long)n * G_ + (w * H_ + lane);
    float x0 = xw[0];
    float x1 = xw[(long)N_ * G_];

    for (int t = 0; t < T_; ++t) {
        float gate = x0;
        x0 = x1;
        if (t + 2 < T_) x1 = xw[(long)(t + 2) * N_ * G_];

        float a0 = 0.f, a1 = 0.f, a2 = 0.f, a3 = 0.f;
        const float4* h4 = (const float4*)hS;
        #define DOT4(i)                          \
            {                                    \
                float4 hv = h4[i];               \
                a0 = fmaf(w##i.x, hv.x, a0);     \
                a1 = fmaf(w##i.y, hv.y, a1);     \
                a2 = fmaf(w##i.z, hv.z, a2);     \
                a3 = fmaf(w##i.w, hv.w, a3);     \
            }
        DOT4(0)  DOT4(1)  DOT4(2)  DOT4(3)
        DOT4(4)  DOT4(5)  DOT4(6)  DOT4(7)
        DOT4(8)  DOT4(9)  DOT4(10) DOT4(11)
        DOT4(12) DOT4(13) DOT4(14) DOT4(15)
        #undef DOT4
        gate += (a0 + a1) + (a2 + a3);

        gbuf[w][lane] = gate;
        __syncthreads();               // B1: gates visible
        if (w == 0) {
            float iv = fast_sig(gate);           // own gate == i
            float fv = fast_sig(gbuf[1][lane]);
            float gv = fast_tanh(gbuf[2][lane]);
            float ov = fast_sig(gbuf[3][lane]);
            ccell = fmaf(fv, ccell, iv * gv);
            hlast = ov * fast_tanh(ccell);
            hS[lane] = hlast;
        }
        __syncthreads();               // B2: new h visible
    }

    if (w == 0) {
        float p = hlast * W_fc[lane];
        #pragma unroll
        for (int m = 1; m < 64; m <<= 1) p += __shfl_xor(p, m);
        if (lane == 0) out[n] = p + b_fc[0];
    }
}

// ---------------------------------------------------------------------------
extern "C" void kernel_launch(void* const* d_in, const int* in_sizes, int n_in,
                              void* d_out, int out_size, void* d_ws, size_t ws_size,
                              hipStream_t stream) {
    const float* x     = (const float*)d_in[0];
    const float* A     = (const float*)d_in[1];
    const float* W_gcn = (const float*)d_in[2];
    const float* b_gcn = (const float*)d_in[3];
    const float* W_ih  = (const float*)d_in[4];
    const float* W_hh  = (const float*)d_in[5];
    const float* b_ih  = (const float*)d_in[6];
    const float* b_hh  = (const float*)d_in[7];
    const float* W_fc  = (const float*)d_in[8];
    const float* b_fc  = (const float*)d_in[9];
    float* out = (float*)d_out;
    float* ws  = (float*)d_ws;

    // 1) fused: copy A->out, a[k][v], sa[k]
    prep_kernel<<<NCOPY + K_, 256, 0, stream>>>(A, out, ws);
    // 2) tiled xa (one block per (n, ci, 64-t chunk))
    xa_kernel<<<N_ * CIN_ * (T_ / TT), 256, 0, stream>>>(x, ws);
    // 3) fused seq + input-side gate GEMM (one block per t)
    seqgates_kernel<<<T_, 256, 0, stream>>>(W_gcn, b_gcn, W_ih, b_ih, b_hh, ws);
    // 4) sequential LSTM scan + final FC
    lstm_kernel<<<N_, 256, 0, stream>>>(W_hh, W_fc, b_fc, ws, out);
}